// Round 1
// baseline (415.587 us; speedup 1.0000x reference)
//
#include <hip/hip_runtime.h>
#include <math.h>

// Shapes fixed by the reference: B=4, N=4096, H=16, D=64; children = 2N.
#define BB 4
#define NN 4096
#define HH 16
#define DD 64
#define ROWS (BB * NN * HH)          // 262144 (b,n,h) rows
#define OUT_ELEMS ((size_t)ROWS * DD)
#define G 2                          // rows per 16-lane group
#define GROUPS (ROWS / G)            // 131072 groups, grid-strided row pairs
#define BLOCK 256

typedef float f4 __attribute__((ext_vector_type(4)));

// DPP row_ror 16-lane butterfly sum (result in all 16 lanes). Pure VALU.
template <int CTRL>
__device__ __forceinline__ float row_ror_add(float v) {
    int s = __builtin_amdgcn_update_dpp(0, __float_as_int(v), CTRL, 0xf, 0xf, true);
    return v + __int_as_float(s);
}
__device__ __forceinline__ float sum16(float v) {
    v = row_ror_add<0x128>(v);   // ror 8
    v = row_ror_add<0x124>(v);   // ror 4
    v = row_ror_add<0x122>(v);   // ror 2
    v = row_ror_add<0x121>(v);   // ror 1
    return v;
}
__device__ __forceinline__ float dot4(f4 a, f4 b) {
    return a.x*b.x + a.y*b.y + a.z*b.z + a.w*b.w;
}
// Plain cached load: lets L2 + Infinity Cache allocate and serve hits at
// hit latency. (NT loads were the single variable changed this round —
// stores remain NT so outputs don't evict cached inputs.)
__device__ __forceinline__ f4 cld(const float* p) {
    return *(const f4*)p;
}

// One 16-lane group handles rows {gid, gid+GROUPS}. Grid-stride keeps every
// load instruction contiguous across the wave (adjacent groups -> adjacent
// rows at each unroll step). All 14 loads are issued before any wait; V
// first so it rides out the reduction+softmax latency.
__global__ __launch_bounds__(BLOCK) void hsa3_kernel(
    const float* __restrict__ Qp, const float* __restrict__ Kp,
    const float* __restrict__ Vp, const float* __restrict__ Kc,
    const float* __restrict__ Vc, float* __restrict__ out,
    float* __restrict__ wout)
{
    const int tid = blockIdx.x * BLOCK + threadIdx.x;
    const int gid = tid >> 4;
    const int l   = tid & 15;
    const int l4  = l << 2;

    const int r0 = gid;
    const int r1 = gid + GROUPS;

    // parent offsets: r*64 + l*4
    const int po0 = (r0 << 6) + l4;
    const int po1 = (r1 << 6) + l4;
    // child offsets: ((bn<<5) + h)*64 + l*4 ; +16*64 for child 1
    const int cb0 = (((r0 >> 4) << 5) + (r0 & 15));
    const int cb1 = (((r1 >> 4) << 5) + (r1 & 15));
    const int c00 = (cb0 << 6) + l4;
    const int c10 = c00 + (HH << 6);
    const int c01 = (cb1 << 6) + l4;
    const int c11 = c01 + (HH << 6);

    // ---- 14 loads, all in flight before first use (V first) ----
    const f4 vp0  = cld(Vp + po0);
    const f4 vc00 = cld(Vc + c00);
    const f4 vc10 = cld(Vc + c10);
    const f4 vp1  = cld(Vp + po1);
    const f4 vc01 = cld(Vc + c01);
    const f4 vc11 = cld(Vc + c11);
    const f4 q0   = cld(Qp + po0);
    const f4 kp0  = cld(Kp + po0);
    const f4 kc00 = cld(Kc + c00);
    const f4 kc10 = cld(Kc + c10);
    const f4 q1   = cld(Qp + po1);
    const f4 kp1  = cld(Kp + po1);
    const f4 kc01 = cld(Kc + c01);
    const f4 kc11 = cld(Kc + c11);

    // ---- dots ----
    float dsA = dot4(q0, kp0), d0A = dot4(q0, kc00), d1A = dot4(q0, kc10);
    float dsB = dot4(q1, kp1), d0B = dot4(q1, kc01), d1B = dot4(q1, kc11);

    dsA = sum16(dsA); d0A = sum16(d0A); d1A = sum16(d1A);
    dsB = sum16(dsB); d0B = sum16(d0B); d1B = sum16(d1B);

    const float scale = 0.125f;            // 1/sqrt(64)
    const float L2E   = 1.44269504088896f; // log2(e)

    // row A softmax
    float s0 = dsA * scale, s1 = d0A * scale, s2 = d1A * scale;
    float mx = fmaxf(s0, fmaxf(s1, s2));
    float e0 = exp2f((s0 - mx) * L2E);
    float e1 = exp2f((s1 - mx) * L2E);
    float e2 = exp2f((s2 - mx) * L2E);
    float inv = __builtin_amdgcn_rcpf(e0 + e1 + e2 + 1e-9f);
    const float w0A = e0 * inv, w1A = e1 * inv, w2A = e2 * inv;

    // row B softmax
    s0 = dsB * scale; s1 = d0B * scale; s2 = d1B * scale;
    mx = fmaxf(s0, fmaxf(s1, s2));
    e0 = exp2f((s0 - mx) * L2E);
    e1 = exp2f((s1 - mx) * L2E);
    e2 = exp2f((s2 - mx) * L2E);
    inv = __builtin_amdgcn_rcpf(e0 + e1 + e2 + 1e-9f);
    const float w0B = e0 * inv, w1B = e1 * inv, w2B = e2 * inv;

    f4 oA, oB;
    oA.x = w0A*vp0.x + w1A*vc00.x + w2A*vc10.x;
    oA.y = w0A*vp0.y + w1A*vc00.y + w2A*vc10.y;
    oA.z = w0A*vp0.z + w1A*vc00.z + w2A*vc10.z;
    oA.w = w0A*vp0.w + w1A*vc00.w + w2A*vc10.w;
    oB.x = w0B*vp1.x + w1B*vc01.x + w2B*vc11.x;
    oB.y = w0B*vp1.y + w1B*vc01.y + w2B*vc11.y;
    oB.z = w0B*vp1.z + w1B*vc01.z + w2B*vc11.z;
    oB.w = w0B*vp1.w + w1B*vc01.w + w2B*vc11.w;

    __builtin_nontemporal_store(oA, (f4*)(out + po0));
    __builtin_nontemporal_store(oB, (f4*)(out + po1));

    // w output: [b,n,h,3] — lanes 0..2 store each row's weights
    if (l < 3) {
        const float wa = (l == 0) ? w0A : ((l == 1) ? w1A : w2A);
        const float wb = (l == 0) ? w0B : ((l == 1) ? w1B : w2B);
        wout[r0 * 3 + l] = wa;
        wout[r1 * 3 + l] = wb;
    }
}

extern "C" void kernel_launch(void* const* d_in, const int* in_sizes, int n_in,
                              void* d_out, int out_size, void* d_ws, size_t ws_size,
                              hipStream_t stream) {
    (void)in_sizes; (void)n_in; (void)d_ws; (void)ws_size; (void)out_size;
    const float* Qp = (const float*)d_in[0];
    const float* Kp = (const float*)d_in[1];
    const float* Vp = (const float*)d_in[2];
    const float* Kc = (const float*)d_in[3];
    const float* Vc = (const float*)d_in[4];
    float* out  = (float*)d_out;
    float* wout = out + OUT_ELEMS;    // tuple: out first, then w

    const int threads = GROUPS * 16;  // 2,097,152
    const int grid = threads / BLOCK; // 8192
    hipLaunchKernelGGL(hsa3_kernel, dim3(grid), dim3(BLOCK), 0, stream,
                       Qp, Kp, Vp, Kc, Vc, out, wout);
}

// Round 2
// 395.552 us; speedup vs baseline: 1.0507x; 1.0507x over previous
//
#include <hip/hip_runtime.h>
#include <math.h>

// Shapes fixed by the reference: B=4, N=4096, H=16, D=64; children = 2N.
#define BB 4
#define NN 4096
#define HH 16
#define DD 64
#define ROWS (BB * NN * HH)          // 262144 (b,n,h) rows
#define OUT_ELEMS ((size_t)ROWS * DD)
#define RPT 4                        // rows per 16-lane group (was 2)
#define QROWS (ROWS / RPT)           // 65536: row k of group g is g + k*QROWS
#define BLOCK 256

typedef float f4 __attribute__((ext_vector_type(4)));

// DPP row_ror 16-lane butterfly sum (result in all 16 lanes). Pure VALU.
template <int CTRL>
__device__ __forceinline__ float row_ror_add(float v) {
    int s = __builtin_amdgcn_update_dpp(0, __float_as_int(v), CTRL, 0xf, 0xf, true);
    return v + __int_as_float(s);
}
__device__ __forceinline__ float sum16(float v) {
    v = row_ror_add<0x128>(v);   // ror 8
    v = row_ror_add<0x124>(v);   // ror 4
    v = row_ror_add<0x122>(v);   // ror 2
    v = row_ror_add<0x121>(v);   // ror 1
    return v;
}
__device__ __forceinline__ float dot4(f4 a, f4 b) {
    return a.x*b.x + a.y*b.y + a.z*b.z + a.w*b.w;
}
// NT loads: PROTECTED. Round-1 A/B showed plain cached loads cost 1.5x
// (103 -> 157 us) at identical FETCH_SIZE — the L1-allocating path
// serializes this streaming pattern; nt bypasses it.
__device__ __forceinline__ f4 ntload(const float* p) {
    return __builtin_nontemporal_load((const f4*)p);
}

// One 16-lane group handles rows {gid + k*QROWS, k=0..3}. Grid-stride keeps
// every load instruction contiguous across the wave. All 28 loads are issued
// before any wait (QK streams first — consumed first; V streams last so they
// ride out the reduction+softmax latency). __launch_bounds__(256,4) caps
// VGPR at 128 so the compiler can keep ~20 loads in flight per wave instead
// of ~5 at the old VGPR=32 allocation.
__global__ __launch_bounds__(BLOCK, 4) void hsa3_kernel(
    const float* __restrict__ Qp, const float* __restrict__ Kp,
    const float* __restrict__ Vp, const float* __restrict__ Kc,
    const float* __restrict__ Vc, float* __restrict__ out,
    float* __restrict__ wout)
{
    const int tid = blockIdx.x * BLOCK + threadIdx.x;
    const int gid = tid >> 4;
    const int l   = tid & 15;
    const int l4  = l << 2;

    int po[RPT], c0[RPT], c1[RPT];
#pragma unroll
    for (int k = 0; k < RPT; ++k) {
        const int r = gid + k * QROWS;
        po[k] = (r << 6) + l4;                       // parent: r*64 + l*4
        const int cb = ((r >> 4) << 5) + (r & 15);   // child base (bn,h) row
        c0[k] = (cb << 6) + l4;
        c1[k] = c0[k] + (HH << 6);                   // sibling child
    }

    // ---- issue all 16 QK loads ----
    f4 q[RPT], kp[RPT], kc0[RPT], kc1[RPT];
#pragma unroll
    for (int k = 0; k < RPT; ++k) {
        q[k]   = ntload(Qp + po[k]);
        kp[k]  = ntload(Kp + po[k]);
        kc0[k] = ntload(Kc + c0[k]);
        kc1[k] = ntload(Kc + c1[k]);
    }
    // ---- issue all 12 V loads (consumed last) ----
    f4 vp[RPT], vc0[RPT], vc1[RPT];
#pragma unroll
    for (int k = 0; k < RPT; ++k) {
        vp[k]  = ntload(Vp + po[k]);
        vc0[k] = ntload(Vc + c0[k]);
        vc1[k] = ntload(Vc + c1[k]);
    }

    const float scale = 0.125f;            // 1/sqrt(64)
    const float L2E   = 1.44269504088896f; // log2(e)

    // ---- consume QK in arrival order: dots + reduce + softmax per row ----
    float w0[RPT], w1[RPT], w2[RPT];
#pragma unroll
    for (int k = 0; k < RPT; ++k) {
        float ds = sum16(dot4(q[k], kp[k]));
        float d0 = sum16(dot4(q[k], kc0[k]));
        float d1 = sum16(dot4(q[k], kc1[k]));
        const float s0 = ds * scale, s1 = d0 * scale, s2 = d1 * scale;
        const float mx = fmaxf(s0, fmaxf(s1, s2));
        const float e0 = exp2f((s0 - mx) * L2E);
        const float e1 = exp2f((s1 - mx) * L2E);
        const float e2 = exp2f((s2 - mx) * L2E);
        const float inv = __builtin_amdgcn_rcpf(e0 + e1 + e2 + 1e-9f);
        w0[k] = e0 * inv; w1[k] = e1 * inv; w2[k] = e2 * inv;
    }

    // ---- consume V: weighted combine + stores ----
#pragma unroll
    for (int k = 0; k < RPT; ++k) {
        f4 o;
        o.x = w0[k]*vp[k].x + w1[k]*vc0[k].x + w2[k]*vc1[k].x;
        o.y = w0[k]*vp[k].y + w1[k]*vc0[k].y + w2[k]*vc1[k].y;
        o.z = w0[k]*vp[k].z + w1[k]*vc0[k].z + w2[k]*vc1[k].z;
        o.w = w0[k]*vp[k].w + w1[k]*vc0[k].w + w2[k]*vc1[k].w;
        __builtin_nontemporal_store(o, (f4*)(out + po[k]));
    }

    // w output: [b,n,h,3] — lanes 0..2 store each row's weights
    if (l < 3) {
#pragma unroll
        for (int k = 0; k < RPT; ++k) {
            const int r = gid + k * QROWS;
            const float w = (l == 0) ? w0[k] : ((l == 1) ? w1[k] : w2[k]);
            wout[r * 3 + l] = w;
        }
    }
}

extern "C" void kernel_launch(void* const* d_in, const int* in_sizes, int n_in,
                              void* d_out, int out_size, void* d_ws, size_t ws_size,
                              hipStream_t stream) {
    (void)in_sizes; (void)n_in; (void)d_ws; (void)ws_size; (void)out_size;
    const float* Qp = (const float*)d_in[0];
    const float* Kp = (const float*)d_in[1];
    const float* Vp = (const float*)d_in[2];
    const float* Kc = (const float*)d_in[3];
    const float* Vc = (const float*)d_in[4];
    float* out  = (float*)d_out;
    float* wout = out + OUT_ELEMS;    // tuple: out first, then w

    const int threads = (ROWS / RPT) * 16;  // 1,048,576
    const int grid = threads / BLOCK;       // 4096
    hipLaunchKernelGGL(hsa3_kernel, dim3(grid), dim3(BLOCK), 0, stream,
                       Qp, Kp, Vp, Kc, Vc, out, wout);
}

// Round 5
// 390.163 us; speedup vs baseline: 1.0652x; 1.0138x over previous
//
#include <hip/hip_runtime.h>
#include <math.h>

// Shapes fixed by the reference: B=4, N=4096, H=16, D=64; children = 2N.
#define BB 4
#define NN 4096
#define HH 16
#define DD 64
#define ROWS (BB * NN * HH)          // 262144 (b,n,h) rows
#define OUT_ELEMS ((size_t)ROWS * DD)
#define G 2                          // rows per 16-lane group
#define GROUPS (ROWS / G)            // 131072 groups
#define BLOCK 256

typedef float f4 __attribute__((ext_vector_type(4)));

// DPP row_ror 16-lane butterfly sum (result in all 16 lanes). Pure VALU.
template <int CTRL>
__device__ __forceinline__ float row_ror_add(float v) {
    int s = __builtin_amdgcn_update_dpp(0, __float_as_int(v), CTRL, 0xf, 0xf, true);
    return v + __int_as_float(s);
}
__device__ __forceinline__ float sum16(float v) {
    v = row_ror_add<0x128>(v);   // ror 8
    v = row_ror_add<0x124>(v);   // ror 4
    v = row_ror_add<0x122>(v);   // ror 2
    v = row_ror_add<0x121>(v);   // ror 1
    return v;
}
__device__ __forceinline__ float dot4(f4 a, f4 b) {
    return a.x*b.x + a.y*b.y + a.z*b.z + a.w*b.w;
}
// NT loads: PROTECTED. Round-1 A/B showed plain cached loads cost 1.5x
// (103 -> 157 us) at identical FETCH_SIZE — the L1-allocating path
// serializes this streaming pattern; nt bypasses it.
__device__ __forceinline__ f4 ntload(const float* p) {
    return __builtin_nontemporal_load((const f4*)p);
}

// One 16-lane group handles rows {gid, gid+GROUPS}. All 14 loads are issued
// in consumption order (QK first, V last) and PINNED above a
// sched_barrier(0): rounds 0/2 proved the register-minimizing scheduler
// otherwise sinks loads to their uses (VGPR_Count 32/44 << the 56+ needed
// for 14 in-flight results), capping per-wave MLP at ~5. With the pin, the
// compiler must keep all 14 results live and emits its own counted
// s_waitcnt vmcnt(10)/(6)/(3)/(0) at the consumption points.
// NOTE: this kernel cannot hang — no loops, no barriers, no hand waits;
// sched_barrier is compile-time only. Rounds 3-4 "container failed twice"
// is diagnosed as infra flake; this is a verbatim resubmission of round 4.
__global__ __launch_bounds__(BLOCK) void hsa3_kernel(
    const float* __restrict__ Qp, const float* __restrict__ Kp,
    const float* __restrict__ Vp, const float* __restrict__ Kc,
    const float* __restrict__ Vc, float* __restrict__ out,
    float* __restrict__ wout)
{
    const int tid = blockIdx.x * BLOCK + threadIdx.x;
    const int gid = tid >> 4;
    const int l   = tid & 15;
    const int l4  = l << 2;

    const int r0 = gid;
    const int r1 = gid + GROUPS;

    // parent offsets: r*64 + l*4
    const int po0 = (r0 << 6) + l4;
    const int po1 = (r1 << 6) + l4;
    // child offsets: ((bn<<5) + h)*64 + l*4 ; +16*64 for child 1
    const int cb0 = (((r0 >> 4) << 5) + (r0 & 15));
    const int cb1 = (((r1 >> 4) << 5) + (r1 & 15));
    const int c00 = (cb0 << 6) + l4;
    const int c10 = c00 + (HH << 6);
    const int c01 = (cb1 << 6) + l4;
    const int c11 = c01 + (HH << 6);

    // ---- issue all 14 loads in consumption order: row-A QK, row-B QK,
    // ---- row-A V, row-B V ----
    const f4 q0   = ntload(Qp + po0);
    const f4 kp0  = ntload(Kp + po0);
    const f4 kc00 = ntload(Kc + c00);
    const f4 kc10 = ntload(Kc + c10);
    const f4 q1   = ntload(Qp + po1);
    const f4 kp1  = ntload(Kp + po1);
    const f4 kc01 = ntload(Kc + c01);
    const f4 kc11 = ntload(Kc + c11);
    const f4 vp0  = ntload(Vp + po0);
    const f4 vc00 = ntload(Vc + c00);
    const f4 vc10 = ntload(Vc + c10);
    const f4 vp1  = ntload(Vp + po1);
    const f4 vc01 = ntload(Vc + c01);
    const f4 vc11 = ntload(Vc + c11);

    // PIN: nothing below may be scheduled above this point, and the loads
    // above may not sink below it. This is the whole experiment.
    __builtin_amdgcn_sched_barrier(0);

    const float scale = 0.125f;            // 1/sqrt(64)
    const float L2E   = 1.44269504088896f; // log2(e)

    // ---- row A (first 4 loads): dots + reduce + softmax ----
    float dsA = sum16(dot4(q0, kp0));
    float d0A = sum16(dot4(q0, kc00));
    float d1A = sum16(dot4(q0, kc10));
    float s0 = dsA * scale, s1 = d0A * scale, s2 = d1A * scale;
    float mx = fmaxf(s0, fmaxf(s1, s2));
    float e0 = exp2f((s0 - mx) * L2E);
    float e1 = exp2f((s1 - mx) * L2E);
    float e2 = exp2f((s2 - mx) * L2E);
    float inv = __builtin_amdgcn_rcpf(e0 + e1 + e2 + 1e-9f);
    const float w0A = e0 * inv, w1A = e1 * inv, w2A = e2 * inv;

    // ---- row B (next 4 loads) ----
    float dsB = sum16(dot4(q1, kp1));
    float d0B = sum16(dot4(q1, kc01));
    float d1B = sum16(dot4(q1, kc11));
    s0 = dsB * scale; s1 = d0B * scale; s2 = d1B * scale;
    mx = fmaxf(s0, fmaxf(s1, s2));
    e0 = exp2f((s0 - mx) * L2E);
    e1 = exp2f((s1 - mx) * L2E);
    e2 = exp2f((s2 - mx) * L2E);
    inv = __builtin_amdgcn_rcpf(e0 + e1 + e2 + 1e-9f);
    const float w0B = e0 * inv, w1B = e1 * inv, w2B = e2 * inv;

    // ---- combine + stores, in V arrival order ----
    f4 oA, oB;
    oA.x = w0A*vp0.x + w1A*vc00.x + w2A*vc10.x;
    oA.y = w0A*vp0.y + w1A*vc00.y + w2A*vc10.y;
    oA.z = w0A*vp0.z + w1A*vc00.z + w2A*vc10.z;
    oA.w = w0A*vp0.w + w1A*vc00.w + w2A*vc10.w;
    __builtin_nontemporal_store(oA, (f4*)(out + po0));

    oB.x = w0B*vp1.x + w1B*vc01.x + w2B*vc11.x;
    oB.y = w0B*vp1.y + w1B*vc01.y + w2B*vc11.y;
    oB.z = w0B*vp1.z + w1B*vc01.z + w2B*vc11.z;
    oB.w = w0B*vp1.w + w1B*vc01.w + w2B*vc11.w;
    __builtin_nontemporal_store(oB, (f4*)(out + po1));

    // w output: [b,n,h,3] — lanes 0..2 store each row's weights
    if (l < 3) {
        const float wa = (l == 0) ? w0A : ((l == 1) ? w1A : w2A);
        const float wb = (l == 0) ? w0B : ((l == 1) ? w1B : w2B);
        wout[r0 * 3 + l] = wa;
        wout[r1 * 3 + l] = wb;
    }
}

extern "C" void kernel_launch(void* const* d_in, const int* in_sizes, int n_in,
                              void* d_out, int out_size, void* d_ws, size_t ws_size,
                              hipStream_t stream) {
    (void)in_sizes; (void)n_in; (void)d_ws; (void)ws_size; (void)out_size;
    const float* Qp = (const float*)d_in[0];
    const float* Kp = (const float*)d_in[1];
    const float* Vp = (const float*)d_in[2];
    const float* Kc = (const float*)d_in[3];
    const float* Vc = (const float*)d_in[4];
    float* out  = (float*)d_out;
    float* wout = out + OUT_ELEMS;    // tuple: out first, then w

    const int threads = GROUPS * 16;  // 2,097,152
    const int grid = threads / BLOCK; // 8192
    hipLaunchKernelGGL(hsa3_kernel, dim3(grid), dim3(BLOCK), 0, stream,
                       Qp, Kp, Vp, Kc, Vc, out, wout);
}